// Round 11
// baseline (181.808 us; speedup 1.0000x reference)
//
#include <hip/hip_runtime.h>

#define HW 224
#define NIMG 64
#define NPIX ((size_t)NIMG * HW * HW)
#define ACC_STRIDE 128           // ints per combo in global accumulator
#define NCOMBO (NIMG * 15)       // 960
#define ACC_BYTES (NCOMBO * ACC_STRIDE * 4)   // 491520

typedef unsigned long long u64;

// ---------------- mask helpers: 64-bit and 128-bit flavors -----------------
struct U128 { u64 lo, hi; };

__device__ __forceinline__ u64  u_or  (u64 a, u64 b){ return a | b; }
__device__ __forceinline__ u64  u_and (u64 a, u64 b){ return a & b; }
__device__ __forceinline__ u64  u_andn(u64 a, u64 b){ return a & ~b; }
__device__ __forceinline__ bool u_eq(u64 a, u64 b){ return a == b; }
__device__ __forceinline__ bool u_nz(u64 a){ return a != 0ull; }
__device__ __forceinline__ u64  u_shl(u64 a, int n){ return a << n; }
__device__ __forceinline__ u64  u_shr(u64 a, int n){ return a >> n; }
__device__ __forceinline__ int  u_pop(u64 a){ return __popcll(a); }
__device__ __forceinline__ u64  u_low(u64 a){ return a & (0ull - a); }

__device__ __forceinline__ U128 u_or  (U128 a, U128 b){ return {a.lo|b.lo, a.hi|b.hi}; }
__device__ __forceinline__ U128 u_and (U128 a, U128 b){ return {a.lo&b.lo, a.hi&b.hi}; }
__device__ __forceinline__ U128 u_andn(U128 a, U128 b){ return {a.lo&~b.lo, a.hi&~b.hi}; }
__device__ __forceinline__ bool u_eq(U128 a, U128 b){ return a.lo==b.lo && a.hi==b.hi; }
__device__ __forceinline__ bool u_nz(U128 a){ return (a.lo | a.hi) != 0ull; }
__device__ __forceinline__ U128 u_shl(U128 a, int n){           // 1 <= n < 64
    return { a.lo << n, (a.hi << n) | (a.lo >> (64 - n)) };
}
__device__ __forceinline__ U128 u_shr(U128 a, int n){
    return { (a.lo >> n) | (a.hi << (64 - n)), a.hi >> n };
}
__device__ __forceinline__ int u_pop(U128 a){ return __popcll(a.lo) + __popcll(a.hi); }
__device__ __forceinline__ U128 u_low(U128 a){
    if (a.lo) return { a.lo & (0ull - a.lo), 0ull };
    return { 0ull, a.hi & (0ull - a.hi) };
}

__device__ __forceinline__ void setbit(u64& m, int cb, u64 bit){ m |= bit << cb; }
__device__ __forceinline__ void setbit(U128& m, int cb, u64 bit){
    if (cb < 64) m.lo |= bit << cb; else m.hi |= bit << (cb - 64);
}

template<bool B, class T, class F> struct sel        { using type = T; };
template<class T, class F>         struct sel<false, T, F> { using type = F; };

// ---------------- vectorized N-float row load (exact, no overread) ---------
template<int N>
__device__ __forceinline__ void load_rowN(const float* __restrict__ p, float* r) {
#pragma unroll
    for (int j = 0; j + 4 <= N; j += 4) {
        float4 v; __builtin_memcpy(&v, p + j, 16);
        r[j] = v.x; r[j + 1] = v.y; r[j + 2] = v.z; r[j + 3] = v.w;
    }
    if constexpr ((N & 3) >= 2) {
        constexpr int b = (N / 4) * 4;
        float2 v; __builtin_memcpy(&v, p + b, 8);
        r[b] = v.x; r[b + 1] = v.y;
    }
    if constexpr (N & 1) r[N - 1] = p[N - 1];
}

template<int K>
__device__ __forceinline__ void make_colmasks(u64& lcl, u64& lch, u64& rcl, u64& rch) {
    lcl = lch = rcl = rch = 0;
#pragma unroll
    for (int i = 0; i < K; i++) {
        const int cl = i * K, cr = i * K + K - 1;
        if (cl < 64) lcl |= 1ull << cl; else lch |= 1ull << (cl - 64);
        if (cr < 64) rcl |= 1ull << cr; else rch |= 1ull << (cr - 64);
    }
}

// ---------------- per-mask stats: ones/CC/marea/perc/hist (r8-proven) ------
template<int K, class M>
__device__ __forceinline__ void finish_mask(M msk, M leftCol, M rightCol,
                                            int* hist, int& t_perc,
                                            int& t_ncomp, int& t_marea) {
    constexpr int KK = K * K;
    const int ones = u_pop(msk);

    // singleton fast path: set bits with no set 4-neighbor = 1-px components
    M nbm = u_or(u_or(u_shl(u_andn(msk, rightCol), 1),
                      u_shr(u_andn(msk, leftCol ), 1)),
                 u_or(u_shl(msk, K), u_shr(msk, K)));
    M iso = u_andn(msk, nbm);
    const int niso = u_pop(iso);
    int ncomp = niso, maxsz = (niso > 0) ? 1 : 0;
    M m = u_andn(msk, iso);
    while (u_nz(m)) {                        // multi-pixel clusters only
        M s = u_low(m);
        for (;;) {
            M g = u_or(s, u_or(u_or(u_shl(u_andn(s, rightCol), 1),
                                    u_shr(u_andn(s, leftCol ), 1)),
                               u_or(u_shl(s, K), u_shr(s, K))));
            g = u_and(g, m);
            if (u_eq(g, s)) break;
            s = g;
        }
        ncomp++;
        const int sz = u_pop(s);
        if (sz > maxsz) maxsz = sz;
        m = u_andn(m, s);
    }

    const int bgcnt = KK - ones;
    const int marea = (bgcnt > maxsz) ? bgcnt : maxsz;
    t_ncomp += ncomp;
    t_marea += marea;
    if ((float)ones / (float)KK >= 0.59275f) t_perc++;
    atomicAdd(&hist[ones], 1);               // LDS atomic, no return
}

// ---------------- per-patch, ALL 3 CHANNELS from interleaved NHWC ----------
// A patch row = 3K CONTIGUOUS floats in NHWC -> vector loads; one set of
// loads + addressing feeds 3 masks (was 3 separate planar blocks).
template<int K, class M>
__device__ __forceinline__ void do_patch3(const float* __restrict__ img3, int p,
                                          M leftCol, M rightCol,
                                          int hist[3][124],
                                          int* tp, int* tn, int* tm) {
    constexpr int ROWS = (HW + K - 1) / K;
    constexpr int PAD  = (ROWS * K - HW) / 2;   // 3 for K=11, else 0

    const int pr = p / ROWS, pc = p - pr * ROWS;
    const int y0 = pr * K - PAD, x0 = pc * K - PAD;

    M m0, m1, m2;
    if constexpr (sizeof(M) == 8) { m0 = 0ull; m1 = 0ull; m2 = 0ull; }
    else { m0 = U128{0,0}; m1 = U128{0,0}; m2 = U128{0,0}; }

    const bool fast = (y0 >= 0) && (x0 >= 0) && (y0 + K <= HW) && (x0 + K <= HW);
    if (fast) {
        if constexpr (K <= 5) {
            // full patch tile in registers (3K*K <= 75 floats)
            float t[K][3 * K];
#pragma unroll
            for (int i = 0; i < K; i++)
                load_rowN<3 * K>(img3 + ((size_t)(y0 + i) * HW + x0) * 3, t[i]);
            const float c0 = t[K / 2][3 * (K / 2) + 0];
            const float c1 = t[K / 2][3 * (K / 2) + 1];
            const float c2 = t[K / 2][3 * (K / 2) + 2];
#pragma unroll
            for (int i = 0; i < K; i++) {
#pragma unroll
                for (int j = 0; j < K; j++) {
                    const int cb = i * K + j;
                    setbit(m0, cb, (fabsf(t[i][3*j+0] - c0) <= (float)K) ? 1ull : 0ull);
                    setbit(m1, cb, (fabsf(t[i][3*j+1] - c1) <= (float)K) ? 1ull : 0ull);
                    setbit(m2, cb, (fabsf(t[i][3*j+2] - c2) <= (float)K) ? 1ull : 0ull);
                }
            }
        } else {
            // stream rows; centers loaded upfront (always in-bounds)
            const float* cp = img3 + ((size_t)(y0 + K / 2) * HW + (x0 + K / 2)) * 3;
            const float c0 = cp[0], c1 = cp[1], c2 = cp[2];
#pragma unroll
            for (int i = 0; i < K; i++) {
                float t[3 * K];
                load_rowN<3 * K>(img3 + ((size_t)(y0 + i) * HW + x0) * 3, t);
#pragma unroll
                for (int j = 0; j < K; j++) {
                    const int cb = i * K + j;
                    setbit(m0, cb, (fabsf(t[3*j+0] - c0) <= (float)K) ? 1ull : 0ull);
                    setbit(m1, cb, (fabsf(t[3*j+1] - c1) <= (float)K) ? 1ull : 0ull);
                    setbit(m2, cb, (fabsf(t[3*j+2] - c2) <= (float)K) ? 1ull : 0ull);
                }
            }
        }
    } else {
        // edge patch: scalar loads with zero-pad bounds checks
        const float* cp = img3 + ((size_t)(y0 + K / 2) * HW + (x0 + K / 2)) * 3;
        const float c0 = cp[0], c1 = cp[1], c2 = cp[2];
#pragma unroll
        for (int i = 0; i < K; i++) {
            const int y = y0 + i;
            const bool yin = (unsigned)y < (unsigned)HW;
#pragma unroll
            for (int j = 0; j < K; j++) {
                const int x = x0 + j;
                const bool inb = yin && ((unsigned)x < (unsigned)HW);
                const float* q = img3 + ((size_t)y * HW + x) * 3;
                const float v0 = inb ? q[0] : 0.0f;
                const float v1 = inb ? q[1] : 0.0f;
                const float v2 = inb ? q[2] : 0.0f;
                const int cb = i * K + j;
                setbit(m0, cb, (fabsf(v0 - c0) <= (float)K) ? 1ull : 0ull);
                setbit(m1, cb, (fabsf(v1 - c1) <= (float)K) ? 1ull : 0ull);
                setbit(m2, cb, (fabsf(v2 - c2) <= (float)K) ? 1ull : 0ull);
            }
        }
    }

    finish_mask<K, M>(m0, leftCol, rightCol, hist[0], tp[0], tn[0], tm[0]);
    finish_mask<K, M>(m1, leftCol, rightCol, hist[1], tp[1], tn[1], tm[1]);
    finish_mask<K, M>(m2, leftCol, rightCol, hist[2], tp[2], tn[2], tm[2]);
}

// ---------------- per-wave job: one patch-slice, 3 channels ----------------
// Single wave per block; per-wave private LDS hists; no barriers anywhere.
template<int K>
__device__ __forceinline__ void job_body3(const float* __restrict__ img3,
                                          int slice, int lane, int hist[3][124],
                                          int* __restrict__ gout_b, int kidx) {
    constexpr int ROWS = (HW + K - 1) / K;
    constexpr int P    = ROWS * ROWS;
    constexpr int KK   = K * K;
    // slices per K chosen so each slice ~= 64 patches (>=98% lane util),
    // total 109 blocks/image -> 6976 blocks, heavy-K dispatched first.
    constexpr int SLC  = (K == 3) ? 44 : (K == 5) ? 32 : (K == 7) ? 16
                       : (K == 9) ? 10 : 7;
    using M = typename sel<(KK <= 64), u64, U128>::type;

    u64 lcl, lch, rcl, rch;
    make_colmasks<K>(lcl, lch, rcl, rch);
    M leftCol, rightCol;
    if constexpr (KK <= 64) { leftCol = lcl; rightCol = rcl; }
    else { leftCol = U128{lcl, lch}; rightCol = U128{rcl, rch}; }

#pragma unroll
    for (int ch = 0; ch < 3; ch++)
        for (int s = lane; s <= KK; s += 64) hist[ch][s] = 0;

    const int pstart = (slice * P) / SLC;
    const int pend   = ((slice + 1) * P) / SLC;

    int tp[3] = {0,0,0}, tn[3] = {0,0,0}, tm[3] = {0,0,0};
    for (int p = pstart + lane; p < pend; p += 64)
        do_patch3<K, M>(img3, p, leftCol, rightCol, hist, tp, tn, tm);

    // wave-level reduction of the 9 scalars
#pragma unroll
    for (int off = 32; off; off >>= 1) {
#pragma unroll
        for (int ch = 0; ch < 3; ch++) {
            tp[ch] += __shfl_down(tp[ch], off);
            tn[ch] += __shfl_down(tn[ch], off);
            tm[ch] += __shfl_down(tm[ch], off);
        }
    }
    if (lane == 0) {
#pragma unroll
        for (int ch = 0; ch < 3; ch++) {
            int* gout = gout_b + (ch * 5 + kidx) * ACC_STRIDE;
            atomicAdd(&gout[124], tp[ch]);
            atomicAdd(&gout[125], tn[ch]);
            atomicAdd(&gout[126], tm[ch]);
        }
    }
    // sparse merge of this wave's hists (same-wave DS ordering: in-order)
#pragma unroll
    for (int ch = 0; ch < 3; ch++) {
        int* gout = gout_b + (ch * 5 + kidx) * ACC_STRIDE;
        for (int s = lane; s <= KK; s += 64) {
            const int v = hist[ch][s];
            if (v) atomicAdd(&gout[s], v);
        }
    }
}

// grid = 64 images * 109 slice-jobs = 6976 one-wave blocks, reading the
// interleaved NHWC input directly (a patch row = 3K contiguous floats).
// XCD swizzle: all 109 blocks of image b land on xcd = b % 8.
__global__ __launch_bounds__(64) void fractal_stats3(const float* __restrict__ in,
                                                     int* __restrict__ gacc) {
    const int lane  = threadIdx.x;
    const int B     = blockIdx.x;
    const int x     = B & 7;
    const int j     = B >> 3;                // 0..871
    const int gl    = j / 109;               // 0..7
    const int inner = j - gl * 109;          // 0..108
    const int b     = gl * 8 + x;            // 0..63

    __shared__ int hist[3][124];             // this block's single wave owns all

    int kidx, slice;                         // heavy K first (drain tail)
    if      (inner < 7)  { kidx = 4; slice = inner;      }
    else if (inner < 17) { kidx = 3; slice = inner - 7;  }
    else if (inner < 33) { kidx = 2; slice = inner - 17; }
    else if (inner < 77) { kidx = 0; slice = inner - 33; }
    else                 { kidx = 1; slice = inner - 77; }

    const float* img3 = in + (size_t)b * HW * HW * 3;
    int* gout_b = gacc + (size_t)b * 15 * ACC_STRIDE;

    switch (kidx) {                          // block-uniform branch
        case 0: job_body3<3 >(img3, slice, lane, hist, gout_b, 0); break;
        case 1: job_body3<5 >(img3, slice, lane, hist, gout_b, 1); break;
        case 2: job_body3<7 >(img3, slice, lane, hist, gout_b, 2); break;
        case 3: job_body3<9 >(img3, slice, lane, hist, gout_b, 3); break;
        case 4: job_body3<11>(img3, slice, lane, hist, gout_b, 4); break;
    }
}

// ---------------- stage 2: finalize (4x redundant) + 56-row resize strip ---
// grid (4, NIMG) x 256: threads 0..14 recompute this image's 15 combos from
// gacc (exact same summation order as r4..r10 -> identical numerics),
// barrier, then each block bilinear-fills rows [q*56, q*56+56).
__global__ __launch_bounds__(256) void fractal_resize_acc(const int* __restrict__ gacc,
                                                          float* __restrict__ out,
                                                          int total) {
    const int q = blockIdx.x, b = blockIdx.y;
    __shared__ float vals[75];               // [metric(5)][kidx(5)][ch(3)]

    if (threadIdx.x < 15) {
        const int rem  = threadIdx.x;
        const int ch   = rem / 5;
        const int kidx = rem % 5;
        const int K    = 3 + 2 * kidx;
        const int ROWS = (HW + K - 1) / K;
        const int P    = ROWS * ROWS;
        const int KK   = K * K;

        const int* a = gacc + (b * 15 + rem) * ACC_STRIDE;
        const float Pf = (float)P;
        float fd = 0.0f, m1 = 0.0f, m2 = 0.0f;
        for (int s = 0; s < KK; s++) {       // bin KK (ones==K*K) excluded
            const float prob = (float)a[s] / Pf;
            const float n = (float)(s + 1);
            fd += prob / n;
            m1 += prob * n;
            m2 += prob * prob * n;
        }
        const float lac = (m2 - m1 * m1) / (m1 * m1);
        vals[(0 * 5 + kidx) * 3 + ch] = (float)(a[125] / P);  // acn
        vals[(1 * 5 + kidx) * 3 + ch] = (float)(a[124] / P);  // acp
        vals[(2 * 5 + kidx) * 3 + ch] = (float)(a[126] / P);  // acma
        vals[(3 * 5 + kidx) * 3 + ch] = lac;
        vals[(4 * 5 + kidx) * 3 + ch] = fd;
    }
    __syncthreads();

    const int x = threadIdx.x;
    if (x >= HW) return;

    // x-interpolation hoisted out of the row loop
    const float sc = 5.0f / 224.0f;
    const float ux = ((float)x + 0.5f) * sc - 0.5f;
    const float fx = floorf(ux);
    const float wx = ux - fx;
    int x0 = (int)fx, x1 = x0 + 1;
    if (x0 < 0) x0 = 0; if (x1 > 4) x1 = 4;

    for (int y = q * 56; y < q * 56 + 56; ++y) {
        const float uy = ((float)y + 0.5f) * sc - 0.5f;
        const float fy = floorf(uy);
        const float wy = uy - fy;
        int y0 = (int)fy, y1 = y0 + 1;
        if (y0 < 0) y0 = 0; if (y1 > 4) y1 = 4;

        const float w00 = (1.0f - wy) * (1.0f - wx), w01 = (1.0f - wy) * wx;
        const float w10 = wy * (1.0f - wx),          w11 = wy * wx;

        const int base = ((b * HW + y) * HW + x) * 3;
        if (base + 3 > total) continue;
#pragma unroll
        for (int ch = 0; ch < 3; ch++) {
            out[base + ch] = w00 * vals[(y0 * 5 + x0) * 3 + ch]
                           + w01 * vals[(y0 * 5 + x1) * 3 + ch]
                           + w10 * vals[(y1 * 5 + x0) * 3 + ch]
                           + w11 * vals[(y1 * 5 + x1) * 3 + ch];
        }
    }
}

// ---------------- monolithic fallback (interleaved input, tiny ws) ---------
template<int K>
__device__ __forceinline__ void stats_body_full(const float* __restrict__ img3,
                                                float* __restrict__ o,
                                                int hist4[4][124], int* sums) {
    constexpr int KK   = K * K;
    constexpr int ROWS = (HW + K - 1) / K;
    constexpr int P    = ROWS * ROWS;
    constexpr int PAD  = (ROWS * K - HW) / 2;
    using M = typename sel<(KK <= 64), u64, U128>::type;
    const int wid = threadIdx.x >> 6;

    u64 lcl, lch, rcl, rch;
    make_colmasks<K>(lcl, lch, rcl, rch);
    M leftCol, rightCol;
    if constexpr (KK <= 64) { leftCol = lcl; rightCol = rcl; }
    else { leftCol = U128{lcl, lch}; rightCol = U128{rcl, rch}; }

    int t_perc = 0, t_ncomp = 0, t_marea = 0;
    for (int p = threadIdx.x; p < P; p += 256) {
        const int pr = p / ROWS, pc = p - pr * ROWS;
        const int y0 = pr * K - PAD, x0 = pc * K - PAD;
        const float cen = img3[((size_t)(y0 + K / 2) * HW + (x0 + K / 2)) * 3];
        M msk;
        if constexpr (KK <= 64) msk = 0ull; else msk = U128{0, 0};
#pragma unroll
        for (int i = 0; i < K; i++) {
            const int y = y0 + i;
            const bool yin = (unsigned)y < (unsigned)HW;
#pragma unroll
            for (int j = 0; j < K; j++) {
                const int x = x0 + j;
                const bool inb = yin && ((unsigned)x < (unsigned)HW);
                const float v = inb ? img3[((size_t)y * HW + x) * 3] : 0.0f;
                setbit(msk, i * K + j, (fabsf(v - cen) <= (float)K) ? 1ull : 0ull);
            }
        }
        finish_mask<K, M>(msk, leftCol, rightCol, hist4[wid],
                          t_perc, t_ncomp, t_marea);
    }

    atomicAdd(&sums[0], t_perc);
    atomicAdd(&sums[1], t_ncomp);
    atomicAdd(&sums[2], t_marea);
    __syncthreads();

    if (threadIdx.x == 0) {
        const float Pf = (float)P;
        float fd = 0.0f, m1 = 0.0f, m2 = 0.0f;
        for (int s = 0; s < KK; s++) {
            const float prob = (float)(hist4[0][s] + hist4[1][s] + hist4[2][s] + hist4[3][s]) / Pf;
            const float n = (float)(s + 1);
            fd += prob / n;
            m1 += prob * n;
            m2 += prob * prob * n;
        }
        const float lac = (m2 - m1 * m1) / (m1 * m1);
        o[0]  = (float)(sums[1] / P);
        o[15] = (float)(sums[0] / P);
        o[30] = (float)(sums[2] / P);
        o[45] = lac;
        o[60] = fd;
    }
}

__global__ __launch_bounds__(256) void fractal_stats_full(const float* __restrict__ in,
                                                          float* __restrict__ interm) {
    const int b    = blockIdx.x / 15;
    const int rem  = blockIdx.x % 15;
    const int ch   = rem / 5;
    const int kidx = rem % 5;

    __shared__ int hist[4][124];
    __shared__ int sums[3];
    for (int i = threadIdx.x; i < 4 * 124; i += 256) ((int*)hist)[i] = 0;
    if (threadIdx.x < 3) sums[threadIdx.x] = 0;
    __syncthreads();

    const float* img3 = in + (size_t)b * HW * HW * 3 + ch;
    float* o = interm + (size_t)b * 75 + kidx * 3 + ch;

    switch (kidx) {
        case 0: stats_body_full<3 >(img3, o, hist, sums); break;
        case 1: stats_body_full<5 >(img3, o, hist, sums); break;
        case 2: stats_body_full<7 >(img3, o, hist, sums); break;
        case 3: stats_body_full<9 >(img3, o, hist, sums); break;
        case 4: stats_body_full<11>(img3, o, hist, sums); break;
    }
}

// fallback resize from interm
__global__ __launch_bounds__(256) void fractal_resize(const float* __restrict__ interm,
                                                      float* __restrict__ out, int total) {
    const int x = threadIdx.x;
    if (x >= HW) return;
    const int y = blockIdx.x, b = blockIdx.y;

    const float sc = 5.0f / 224.0f;
    const float uy = ((float)y + 0.5f) * sc - 0.5f;
    const float ux = ((float)x + 0.5f) * sc - 0.5f;

    const float fy = floorf(uy), fx = floorf(ux);
    const float wy = uy - fy,    wx = ux - fx;
    int y0 = (int)fy, x0 = (int)fx;
    int y1 = y0 + 1,  x1 = x0 + 1;
    if (y0 < 0) y0 = 0; if (x0 < 0) x0 = 0;
    if (y1 > 4) y1 = 4; if (x1 > 4) x1 = 4;

    const float w00 = (1.0f - wy) * (1.0f - wx), w01 = (1.0f - wy) * wx;
    const float w10 = wy * (1.0f - wx),          w11 = wy * wx;

    const float* gp = interm + (size_t)b * 75;
    const int base = ((b * HW + y) * HW + x) * 3;
    if (base + 3 > total) return;
#pragma unroll
    for (int ch = 0; ch < 3; ch++) {
        out[base + ch] = w00 * gp[(y0 * 5 + x0) * 3 + ch]
                       + w01 * gp[(y0 * 5 + x1) * 3 + ch]
                       + w10 * gp[(y1 * 5 + x0) * 3 + ch]
                       + w11 * gp[(y1 * 5 + x1) * 3 + ch];
    }
}

// ---------------- launcher -------------------------------------------------
extern "C" void kernel_launch(void* const* d_in, const int* in_sizes, int n_in,
                              void* d_out, int out_size, void* d_ws, size_t ws_size,
                              hipStream_t stream) {
    const float* in = (const float*)d_in[0];
    float* out = (float*)d_out;
    float* interm = (float*)d_ws;                    // fallback-path only

    const size_t acc_off = 19456;                    // 16B-aligned
    const size_t need    = acc_off + ACC_BYTES;      // ~0.5 MB

    if (ws_size >= need) {
        int* gacc = (int*)((char*)d_ws + acc_off);
        hipMemsetAsync(gacc, 0, ACC_BYTES, stream);  // graph-capturable
        fractal_stats3<<<64 * 109, 64, 0, stream>>>(in, gacc);
        fractal_resize_acc<<<dim3(4, NIMG), 256, 0, stream>>>(gacc, out, out_size);
    } else {
        fractal_stats_full<<<NIMG * 15, 256, 0, stream>>>(in, interm);
        fractal_resize<<<dim3(HW, NIMG), 256, 0, stream>>>(interm, out, out_size);
    }
}

// Round 12
// 150.761 us; speedup vs baseline: 1.2059x; 1.2059x over previous
//
#include <hip/hip_runtime.h>

#define HW 224
#define NIMG 64
#define NPIX ((size_t)NIMG * HW * HW)
#define NSLICE 8                 // patch-slices per (b,ch,K) combo
#define ACC_STRIDE 128           // ints per combo in global accumulator
#define NCOMBO (NIMG * 15)       // 960
#define ACC_BYTES (NCOMBO * ACC_STRIDE * 4)   // 491520

typedef unsigned long long u64;

// ---------------- mask helpers: 64-bit and 128-bit flavors -----------------
struct U128 { u64 lo, hi; };

__device__ __forceinline__ u64  u_or  (u64 a, u64 b){ return a | b; }
__device__ __forceinline__ u64  u_and (u64 a, u64 b){ return a & b; }
__device__ __forceinline__ u64  u_andn(u64 a, u64 b){ return a & ~b; }
__device__ __forceinline__ bool u_eq(u64 a, u64 b){ return a == b; }
__device__ __forceinline__ bool u_nz(u64 a){ return a != 0ull; }
__device__ __forceinline__ u64  u_shl(u64 a, int n){ return a << n; }
__device__ __forceinline__ u64  u_shr(u64 a, int n){ return a >> n; }
__device__ __forceinline__ int  u_pop(u64 a){ return __popcll(a); }
__device__ __forceinline__ u64  u_low(u64 a){ return a & (0ull - a); }

__device__ __forceinline__ U128 u_or  (U128 a, U128 b){ return {a.lo|b.lo, a.hi|b.hi}; }
__device__ __forceinline__ U128 u_and (U128 a, U128 b){ return {a.lo&b.lo, a.hi&b.hi}; }
__device__ __forceinline__ U128 u_andn(U128 a, U128 b){ return {a.lo&~b.lo, a.hi&~b.hi}; }
__device__ __forceinline__ bool u_eq(U128 a, U128 b){ return a.lo==b.lo && a.hi==b.hi; }
__device__ __forceinline__ bool u_nz(U128 a){ return (a.lo | a.hi) != 0ull; }
__device__ __forceinline__ U128 u_shl(U128 a, int n){           // 1 <= n < 64
    return { a.lo << n, (a.hi << n) | (a.lo >> (64 - n)) };
}
__device__ __forceinline__ U128 u_shr(U128 a, int n){
    return { (a.lo >> n) | (a.hi << (64 - n)), a.hi >> n };
}
__device__ __forceinline__ int u_pop(U128 a){ return __popcll(a.lo) + __popcll(a.hi); }
__device__ __forceinline__ U128 u_low(U128 a){
    if (a.lo) return { a.lo & (0ull - a.lo), 0ull };
    return { 0ull, a.hi & (0ull - a.hi) };
}

template<bool B, class T, class F> struct sel        { using type = T; };
template<class T, class F>         struct sel<false, T, F> { using type = F; };

// ---------------- vectorized K-float row load (exact, no overread) ---------
template<int K>
__device__ __forceinline__ void load_row(const float* __restrict__ p, float* r) {
#pragma unroll
    for (int j = 0; j + 4 <= K; j += 4) {
        float4 v; __builtin_memcpy(&v, p + j, 16);
        r[j] = v.x; r[j + 1] = v.y; r[j + 2] = v.z; r[j + 3] = v.w;
    }
    if constexpr ((K & 3) >= 2) {
        constexpr int b = (K / 4) * 4;
        float2 v; __builtin_memcpy(&v, p + b, 8);
        r[b] = v.x; r[b + 1] = v.y;
    }
    if constexpr (K & 1) r[K - 1] = p[K - 1];
}

// ---------------- per-patch core: binarize + stats -------------------------
// bins: this wave's private LDS histogram
template<int K, int S, class M>
__device__ __forceinline__ void do_patch(const float* __restrict__ img, int p,
                                         M leftCol, M rightCol,
                                         int* bins, int& t_perc, int& t_ncomp,
                                         int& t_marea) {
    constexpr int KK   = K * K;
    constexpr int ROWS = (HW + K - 1) / K;
    constexpr int PAD  = (ROWS * K - HW) / 2;   // 3 for K=11, else 0

    const int pr = p / ROWS, pc = p - pr * ROWS;
    const int y0 = pr * K - PAD, x0 = pc * K - PAD;

    M msk;
    if constexpr (KK <= 64) msk = 0ull; else msk = U128{0, 0};

    const bool fast = (S == 1) && (y0 >= 0) && (x0 >= 0) &&
                      (y0 + K <= HW) && (x0 + K <= HW);
    if (fast) {
        if constexpr (K <= 9) {
            // whole patch in registers: K row-loads issue back-to-back
            // (K-deep memory ILP), center taken from regs (no extra load)
            float r[K][K];
#pragma unroll
            for (int i = 0; i < K; i++)
                load_row<K>(img + (size_t)(y0 + i) * HW + x0, r[i]);
            const float cen = r[K / 2][K / 2];
#pragma unroll
            for (int i = 0; i < K; i++) {
#pragma unroll
                for (int j = 0; j < K; j++) {
                    const u64 bit = (fabsf(r[i][j] - cen) <= (float)K) ? 1ull : 0ull;
                    const int cb = i * K + j;
                    if constexpr (KK <= 64) msk |= bit << cb;
                    else { if (cb < 64) msk.lo |= bit << cb; else msk.hi |= bit << (cb - 64); }
                }
            }
        } else {
            // K=11: stream rows (11 independent row loads = enough ILP)
            const float cen = img[(size_t)(y0 + K / 2) * HW + (x0 + K / 2)];
#pragma unroll
            for (int i = 0; i < K; i++) {
                float r[K];
                load_row<K>(img + (size_t)(y0 + i) * HW + x0, r);
#pragma unroll
                for (int j = 0; j < K; j++) {
                    const u64 bit = (fabsf(r[j] - cen) <= (float)K) ? 1ull : 0ull;
                    const int cb = i * K + j;
                    if constexpr (KK <= 64) msk |= bit << cb;
                    else { if (cb < 64) msk.lo |= bit << cb; else msk.hi |= bit << (cb - 64); }
                }
            }
        }
    } else {
        // edge patch: scalar loads with zero-pad bounds checks
        const float cen = img[((size_t)(y0 + K / 2) * HW + (x0 + K / 2)) * S];
#pragma unroll
        for (int i = 0; i < K; i++) {
            const int y = y0 + i;
            const bool yin = (unsigned)y < (unsigned)HW;
#pragma unroll
            for (int j = 0; j < K; j++) {
                const int x = x0 + j;
                const bool inb = yin && ((unsigned)x < (unsigned)HW);
                const float v = inb ? img[((size_t)y * HW + x) * S] : 0.0f;
                const u64 bit = (fabsf(v - cen) <= (float)K) ? 1ull : 0ull;
                const int cb = i * K + j;
                if constexpr (KK <= 64) msk |= bit << cb;
                else { if (cb < 64) msk.lo |= bit << cb; else msk.hi |= bit << (cb - 64); }
            }
        }
    }
    const int ones = u_pop(msk);

    // connected components: singleton fast path + flood fill for clusters
    M nbm = u_or(u_or(u_shl(u_andn(msk, rightCol), 1),
                      u_shr(u_andn(msk, leftCol ), 1)),
                 u_or(u_shl(msk, K), u_shr(msk, K)));
    M iso = u_andn(msk, nbm);
    const int niso = u_pop(iso);
    int ncomp = niso, maxsz = (niso > 0) ? 1 : 0;
    M m = u_andn(msk, iso);
    while (u_nz(m)) {
        M s = u_low(m);
        for (;;) {
            M g = u_or(s, u_or(u_or(u_shl(u_andn(s, rightCol), 1),
                                    u_shr(u_andn(s, leftCol ), 1)),
                               u_or(u_shl(s, K), u_shr(s, K))));
            g = u_and(g, m);
            if (u_eq(g, s)) break;
            s = g;
        }
        ncomp++;
        const int sz = u_pop(s);
        if (sz > maxsz) maxsz = sz;
        m = u_andn(m, s);
    }

    const int bgcnt = KK - ones;
    const int marea = (bgcnt > maxsz) ? bgcnt : maxsz;
    t_ncomp += ncomp;
    t_marea += marea;
    if ((float)ones / (float)KK >= 0.59275f) t_perc++;
    atomicAdd(&bins[ones], 1);               // LDS atomic: cheap, no return
}

template<int K>
__device__ __forceinline__ void make_colmasks(u64& lcl, u64& lch, u64& rcl, u64& rch) {
    lcl = lch = rcl = rch = 0;
#pragma unroll
    for (int i = 0; i < K; i++) {
        const int cl = i * K, cr = i * K + K - 1;
        if (cl < 64) lcl |= 1ull << cl; else lch |= 1ull << (cl - 64);
        if (cr < 64) rcl |= 1ull << cr; else rch |= 1ull << (cr - 64);
    }
}

// ---------------- per-wave job: one patch-slice ----------------------------
// Single wave per block: all DS ops are same-wave (in-order), no barriers.
template<int K, int S>
__device__ __forceinline__ void job_body(const float* __restrict__ img,
                                         int slice, int lane, int* hist,
                                         int* __restrict__ gout) {
    constexpr int ROWS = (HW + K - 1) / K;
    constexpr int P    = ROWS * ROWS;
    constexpr int KK   = K * K;
    using M = typename sel<(KK <= 64), u64, U128>::type;

    u64 lcl, lch, rcl, rch;
    make_colmasks<K>(lcl, lch, rcl, rch);
    M leftCol, rightCol;
    if constexpr (KK <= 64) { leftCol = lcl; rightCol = rcl; }
    else { leftCol = U128{lcl, lch}; rightCol = U128{rcl, rch}; }

    for (int s = lane; s <= KK; s += 64) hist[s] = 0;

    const int pstart = (slice * P) / NSLICE;
    const int pend   = ((slice + 1) * P) / NSLICE;

    int t_perc = 0, t_ncomp = 0, t_marea = 0;
    if constexpr (K <= 5) {
#pragma unroll 2
        for (int p = pstart + lane; p < pend; p += 64)
            do_patch<K, S, M>(img, p, leftCol, rightCol, hist,
                              t_perc, t_ncomp, t_marea);
    } else {
        for (int p = pstart + lane; p < pend; p += 64)
            do_patch<K, S, M>(img, p, leftCol, rightCol, hist,
                              t_perc, t_ncomp, t_marea);
    }

    // wave-level reduction of the three scalars
#pragma unroll
    for (int off = 32; off; off >>= 1) {
        t_perc  += __shfl_down(t_perc,  off);
        t_ncomp += __shfl_down(t_ncomp, off);
        t_marea += __shfl_down(t_marea, off);
    }
    if (lane == 0) {
        atomicAdd(&gout[124], t_perc);
        atomicAdd(&gout[125], t_ncomp);
        atomicAdd(&gout[126], t_marea);
    }
    // sparse merge of this wave's hist (same-wave DS ordering: in-order)
    for (int s = lane; s <= KK; s += 64) {
        const int v = hist[s];
        if (v) atomicAdd(&gout[s], v);
    }
}

// grid = 192 groups * 5 K * 8 slices = 7680 one-wave blocks (best-measured
// structure across r4/r6/r8/r9/r10/r11 variants).
// XCD swizzle: all 40 blocks of a (b,ch) group land on xcd = group % 8.
template<int S>
__global__ __launch_bounds__(64) void fractal_stats(const float* __restrict__ in,
                                                    int* __restrict__ gacc) {
    const int B     = blockIdx.x;
    const int x     = B & 7;
    const int j     = B >> 3;
    const int gl    = j / 40;
    const int inner = j - gl * 40;
    const int g     = gl * 8 + x;            // 0..191 = b*3 + ch
    const int b     = g / 3, ch = g - b * 3;
    const int kidx  = inner >> 3;
    const int slice = inner & 7;

    __shared__ int hist[124];

    const float* img = (S == 1) ? in + ((size_t)ch * NIMG + b) * HW * HW
                                : in + (size_t)b * HW * HW * 3 + ch;
    int* gout = gacc + (g * 5 + kidx) * ACC_STRIDE;

    switch (kidx) {                          // block-uniform branch
        case 0: job_body<3,  S>(img, slice, threadIdx.x, hist, gout); break;
        case 1: job_body<5,  S>(img, slice, threadIdx.x, hist, gout); break;
        case 2: job_body<7,  S>(img, slice, threadIdx.x, hist, gout); break;
        case 3: job_body<9,  S>(img, slice, threadIdx.x, hist, gout); break;
        case 4: job_body<11, S>(img, slice, threadIdx.x, hist, gout); break;
    }
}

// ---------------- stage 2: finalize (4x redundant) + 56-row resize strip ---
// grid (4, NIMG) x 256: threads 0..14 recompute this image's 15 combos from
// gacc (exact same summation order as the r4/r6 finalize kernel -> identical
// numerics), barrier, then each block bilinear-fills rows [q*56, q*56+56).
__global__ __launch_bounds__(256) void fractal_resize_acc(const int* __restrict__ gacc,
                                                          float* __restrict__ out,
                                                          int total) {
    const int q = blockIdx.x, b = blockIdx.y;
    __shared__ float vals[75];               // [metric(5)][kidx(5)][ch(3)]

    if (threadIdx.x < 15) {
        const int rem  = threadIdx.x;
        const int ch   = rem / 5;
        const int kidx = rem % 5;
        const int K    = 3 + 2 * kidx;
        const int ROWS = (HW + K - 1) / K;
        const int P    = ROWS * ROWS;
        const int KK   = K * K;

        const int* a = gacc + (b * 15 + rem) * ACC_STRIDE;
        const float Pf = (float)P;
        float fd = 0.0f, m1 = 0.0f, m2 = 0.0f;
        for (int s = 0; s < KK; s++) {       // bin KK (ones==K*K) excluded
            const float prob = (float)a[s] / Pf;
            const float n = (float)(s + 1);
            fd += prob / n;
            m1 += prob * n;
            m2 += prob * prob * n;
        }
        const float lac = (m2 - m1 * m1) / (m1 * m1);
        vals[(0 * 5 + kidx) * 3 + ch] = (float)(a[125] / P);  // acn
        vals[(1 * 5 + kidx) * 3 + ch] = (float)(a[124] / P);  // acp
        vals[(2 * 5 + kidx) * 3 + ch] = (float)(a[126] / P);  // acma
        vals[(3 * 5 + kidx) * 3 + ch] = lac;
        vals[(4 * 5 + kidx) * 3 + ch] = fd;
    }
    __syncthreads();

    const int x = threadIdx.x;
    if (x >= HW) return;

    // x-interpolation hoisted out of the row loop
    const float sc = 5.0f / 224.0f;
    const float ux = ((float)x + 0.5f) * sc - 0.5f;
    const float fx = floorf(ux);
    const float wx = ux - fx;
    int x0 = (int)fx, x1 = x0 + 1;
    if (x0 < 0) x0 = 0; if (x1 > 4) x1 = 4;

    for (int y = q * 56; y < q * 56 + 56; ++y) {
        const float uy = ((float)y + 0.5f) * sc - 0.5f;
        const float fy = floorf(uy);
        const float wy = uy - fy;
        int y0 = (int)fy, y1 = y0 + 1;
        if (y0 < 0) y0 = 0; if (y1 > 4) y1 = 4;

        const float w00 = (1.0f - wy) * (1.0f - wx), w01 = (1.0f - wy) * wx;
        const float w10 = wy * (1.0f - wx),          w11 = wy * wx;

        const int base = ((b * HW + y) * HW + x) * 3;
        if (base + 3 > total) continue;
#pragma unroll
        for (int ch = 0; ch < 3; ch++) {
            out[base + ch] = w00 * vals[(y0 * 5 + x0) * 3 + ch]
                           + w01 * vals[(y0 * 5 + x1) * 3 + ch]
                           + w10 * vals[(y1 * 5 + x0) * 3 + ch]
                           + w11 * vals[(y1 * 5 + x1) * 3 + ch];
        }
    }
}

// ---------------- monolithic fallback (interleaved input, small ws) --------
template<int K, int S>
__device__ __forceinline__ void stats_body_full(const float* __restrict__ img,
                                                float* __restrict__ o,
                                                int hist4[4][124], int* sums) {
    constexpr int KK   = K * K;
    constexpr int ROWS = (HW + K - 1) / K;
    constexpr int P    = ROWS * ROWS;
    using M = typename sel<(KK <= 64), u64, U128>::type;
    const int wid = threadIdx.x >> 6;

    u64 lcl, lch, rcl, rch;
    make_colmasks<K>(lcl, lch, rcl, rch);
    M leftCol, rightCol;
    if constexpr (KK <= 64) { leftCol = lcl; rightCol = rcl; }
    else { leftCol = U128{lcl, lch}; rightCol = U128{rcl, rch}; }

    int t_perc = 0, t_ncomp = 0, t_marea = 0;
    for (int p = threadIdx.x; p < P; p += 256)
        do_patch<K, S, M>(img, p, leftCol, rightCol, hist4[wid],
                          t_perc, t_ncomp, t_marea);

    atomicAdd(&sums[0], t_perc);
    atomicAdd(&sums[1], t_ncomp);
    atomicAdd(&sums[2], t_marea);
    __syncthreads();

    if (threadIdx.x == 0) {
        const float Pf = (float)P;
        float fd = 0.0f, m1 = 0.0f, m2 = 0.0f;
        for (int s = 0; s < KK; s++) {
            const float prob = (float)(hist4[0][s] + hist4[1][s] + hist4[2][s] + hist4[3][s]) / Pf;
            const float n = (float)(s + 1);
            fd += prob / n;
            m1 += prob * n;
            m2 += prob * prob * n;
        }
        const float lac = (m2 - m1 * m1) / (m1 * m1);
        o[0]  = (float)(sums[1] / P);
        o[15] = (float)(sums[0] / P);
        o[30] = (float)(sums[2] / P);
        o[45] = lac;
        o[60] = fd;
    }
}

template<int S>
__global__ __launch_bounds__(256) void fractal_stats_full(const float* __restrict__ in,
                                                          float* __restrict__ interm) {
    const int b    = blockIdx.x / 15;
    const int rem  = blockIdx.x % 15;
    const int ch   = rem / 5;
    const int kidx = rem % 5;

    __shared__ int hist[4][124];
    __shared__ int sums[3];
    for (int i = threadIdx.x; i < 4 * 124; i += 256) ((int*)hist)[i] = 0;
    if (threadIdx.x < 3) sums[threadIdx.x] = 0;
    __syncthreads();

    const float* img = in + (size_t)b * HW * HW * 3 + ch;
    float* o = interm + (size_t)b * 75 + kidx * 3 + ch;

    switch (kidx) {
        case 0: stats_body_full<3,  S>(img, o, hist, sums); break;
        case 1: stats_body_full<5,  S>(img, o, hist, sums); break;
        case 2: stats_body_full<7,  S>(img, o, hist, sums); break;
        case 3: stats_body_full<9,  S>(img, o, hist, sums); break;
        case 4: stats_body_full<11, S>(img, o, hist, sums); break;
    }
}

// fallback resize from interm
__global__ __launch_bounds__(256) void fractal_resize(const float* __restrict__ interm,
                                                      float* __restrict__ out, int total) {
    const int x = threadIdx.x;
    if (x >= HW) return;
    const int y = blockIdx.x, b = blockIdx.y;

    const float sc = 5.0f / 224.0f;
    const float uy = ((float)y + 0.5f) * sc - 0.5f;
    const float ux = ((float)x + 0.5f) * sc - 0.5f;

    const float fy = floorf(uy), fx = floorf(ux);
    const float wy = uy - fy,    wx = ux - fx;
    int y0 = (int)fy, x0 = (int)fx;
    int y1 = y0 + 1,  x1 = x0 + 1;
    if (y0 < 0) y0 = 0; if (x0 < 0) x0 = 0;
    if (y1 > 4) y1 = 4; if (x1 > 4) x1 = 4;

    const float w00 = (1.0f - wy) * (1.0f - wx), w01 = (1.0f - wy) * wx;
    const float w10 = wy * (1.0f - wx),          w11 = wy * wx;

    const float* gp = interm + (size_t)b * 75;
    const int base = ((b * HW + y) * HW + x) * 3;
    if (base + 3 > total) return;
#pragma unroll
    for (int ch = 0; ch < 3; ch++) {
        out[base + ch] = w00 * gp[(y0 * 5 + x0) * 3 + ch]
                       + w01 * gp[(y0 * 5 + x1) * 3 + ch]
                       + w10 * gp[(y1 * 5 + x0) * 3 + ch]
                       + w11 * gp[(y1 * 5 + x1) * 3 + ch];
    }
}

// ---------------- NHWC -> planar + accumulator zeroing ---------------------
__global__ __launch_bounds__(256) void deinterleave(const float* __restrict__ in,
                                                    float* __restrict__ planes,
                                                    int* __restrict__ gacc) {
    const int t = blockIdx.x * 256 + threadIdx.x;
    if (t < ACC_BYTES / 16) {                        // zero 128-int accumulators
        const int4 z = make_int4(0, 0, 0, 0);
        ((int4*)gacc)[t] = z;
    }
    const size_t pix = (size_t)t * 4;
    if (pix >= NPIX) return;
    float4 a, b, c;
    __builtin_memcpy(&a, in + pix * 3,     16);
    __builtin_memcpy(&b, in + pix * 3 + 4, 16);
    __builtin_memcpy(&c, in + pix * 3 + 8, 16);
    const float4 p0 = make_float4(a.x, a.w, b.z, c.y);
    const float4 p1 = make_float4(a.y, b.x, b.w, c.z);
    const float4 p2 = make_float4(a.z, b.y, c.x, c.w);
    __builtin_memcpy(planes + pix,            &p0, 16);
    __builtin_memcpy(planes + NPIX + pix,     &p1, 16);
    __builtin_memcpy(planes + 2 * NPIX + pix, &p2, 16);
}

// ---------------- launcher -------------------------------------------------
extern "C" void kernel_launch(void* const* d_in, const int* in_sizes, int n_in,
                              void* d_out, int out_size, void* d_ws, size_t ws_size,
                              hipStream_t stream) {
    const float* in = (const float*)d_in[0];
    float* out = (float*)d_out;
    float* interm = (float*)d_ws;                    // fallback-path only

    const size_t acc_off    = 19456;                 // 16B-aligned
    const size_t planes_off = acc_off + ACC_BYTES;   // 510976, 256B-aligned
    const size_t need = planes_off + 3 * NPIX * sizeof(float);

    if (ws_size >= need) {
        int*   gacc   = (int*)((char*)d_ws + acc_off);
        float* planes = (float*)((char*)d_ws + planes_off);
        deinterleave<<<(int)(NPIX / 4 / 256), 256, 0, stream>>>(in, planes, gacc);
        fractal_stats<1><<<192 * 40, 64, 0, stream>>>(planes, gacc);
        fractal_resize_acc<<<dim3(4, NIMG), 256, 0, stream>>>(gacc, out, out_size);
    } else {
        fractal_stats_full<3><<<NIMG * 15, 256, 0, stream>>>(in, interm);
        fractal_resize<<<dim3(HW, NIMG), 256, 0, stream>>>(interm, out, out_size);
    }
}